// Round 8
// baseline (364.669 us; speedup 1.0000x reference)
//
#include <hip/hip_runtime.h>

#define T_ 64
#define B_ 32
#define P_ 32
#define N_ 1024
#define H_ 128
#define G_ 512   // 4*H

typedef __attribute__((ext_vector_type(8))) _Float16 half8;
typedef __attribute__((ext_vector_type(4))) float f32x4;

__device__ __forceinline__ float rcpf(float x){ return __builtin_amdgcn_rcpf(x); }
__device__ __forceinline__ float sigm(float x){ return rcpf(1.f+__expf(-x)); }
__device__ __forceinline__ float tanh_fast(float x){ return 1.f - 2.f*rcpf(__expf(2.f*x)+1.f); }

// ---------------- Kernel 0: prep (9 blocks) ----------------
// blk 0: Bx fragments (x-projection M + bias hi/lo folded as k-slots 0..5)
// blk 1-8: W fragments, f16, MFMA B-layout: [L][w][n][t][lane][j]
//          g = n*128 + w*16 + (lane&15), k = t*32 + 8*(lane>>4) + j
__global__ __launch_bounds__(256) void prep_kernel(
    const float* __restrict__ W_sp, const float* __restrict__ b_sp,
    const float* __restrict__ W_st, const float* __restrict__ b_st,
    const float* __restrict__ Wih_t, const float* __restrict__ Whh_t,
    const float* __restrict__ bih_t, const float* __restrict__ bhh_t,
    const float* __restrict__ Wih_s, const float* __restrict__ Whh_s,
    const float* __restrict__ bih_s, const float* __restrict__ bhh_s,
    _Float16* __restrict__ Wfrag, _Float16* __restrict__ Bxfrag)
{
  const int tid = threadIdx.x;
  const int blk = blockIdx.x;
  if (blk == 0) {
    // zero the whole Bx region first (lanes>=16 and j=6,7 must be 0)
    unsigned int* bz = (unsigned int*)Bxfrag;
    for (int i = tid; i < 16384; i += 256) bz[i] = 0u;
    __syncthreads();
    for (int g = tid; g < G_; g += 256) {
      const int wv = (g & 127) >> 4, n = g >> 7, lane = g & 15;
      {
        float m0=0.f,m1=0.f,bt=0.f;
        for (int e=0;e<H_;e++){ float wgt=Wih_t[g*H_+e]; m0+=wgt*W_sp[e*2]; m1+=wgt*W_sp[e*2+1]; bt+=wgt*b_sp[e]; }
        const float bsum = bt + bih_t[g] + bhh_t[g];
        _Float16* dst = Bxfrag + (((0*8+wv)*4+n)*64 + lane)*8;
        dst[0]=(_Float16)m0; dst[1]=(_Float16)m1; dst[2]=(_Float16)0.f; dst[3]=(_Float16)0.f;
        const _Float16 bh = (_Float16)bsum;
        dst[4]=bh; dst[5]=(_Float16)(bsum-(float)bh);
      }
      {
        float s0=0.f,s1=0.f,s2=0.f,s3=0.f,bs=0.f;
        for (int e=0;e<H_;e++){ float wgt=Wih_s[g*H_+e]; s0+=wgt*W_st[e*4]; s1+=wgt*W_st[e*4+1]; s2+=wgt*W_st[e*4+2]; s3+=wgt*W_st[e*4+3]; bs+=wgt*b_st[e]; }
        const float bsum = bs + bih_s[g] + bhh_s[g];
        _Float16* dst = Bxfrag + (((1*8+wv)*4+n)*64 + lane)*8;
        dst[0]=(_Float16)s0; dst[1]=(_Float16)s1; dst[2]=(_Float16)s2; dst[3]=(_Float16)s3;
        const _Float16 bh = (_Float16)bsum;
        dst[4]=bh; dst[5]=(_Float16)(bsum-(float)bh);
      }
    }
  } else {
    const int L = (blk-1) >> 2;           // lstm
    const int q = (blk-1) & 3;            // quarter
    const float* Whh = L ? Whh_s : Whh_t;
    for (int e = q*16384 + tid; e < (q+1)*16384; e += 256) {
      const int j  = e & 7;
      const int l  = (e >> 3) & 63;
      const int t  = (e >> 9) & 3;
      const int n  = (e >> 11) & 3;
      const int w  = (e >> 13) & 7;
      const int g  = n*128 + w*16 + (l & 15);
      const int k  = t*32 + 8*(l >> 4) + j;
      Wfrag[L*65536 + e] = (_Float16)Whh[g*H_ + k];
    }
  }
}

// ---------------- Kernel 1: both masked LSTMs, MFMA ----------------
// Same structure as R7 (8 rows/block, 8 waves, x+bias folded into MFMA,
// shfl-split activation: 2 real cells/lane, f16 h). New: the per-step MFMA
// dependency chain is split into two parallel chains (depth 3+2 instead of 5)
// and merged with one vector add — shortens the serial critical path.
__global__ __launch_bounds__(512) __attribute__((amdgpu_waves_per_eu(2,2)))
void lstm_kernel(
    const float* __restrict__ rel, const float* __restrict__ pvx,
    const float* __restrict__ pvy, const float* __restrict__ pax,
    const float* __restrict__ pay, const int* __restrict__ maskI,
    const _Float16* __restrict__ Wfrag, const _Float16* __restrict__ Bxfrag,
    float* __restrict__ h_t_out, float* __restrict__ h_s_out)
{
  __shared__ _Float16 hA[2][4][64][8] __align__(16);   // h f16, dbuf, 8KB
  __shared__ _Float16 axf[T_][16][8] __align__(16);    // x A-frags, 16KB
  __shared__ _Float16 zslot[8] __align__(16);
  __shared__ unsigned int ml[T_];

  const int lstm = blockIdx.y;
  const int tid  = threadIdx.x;
  const int w    = tid >> 6;
  const int l    = tid & 63;
  const int n0   = blockIdx.x * 8;
  const int u    = w*16 + (l & 15);
  const int kt_u = u >> 5;

  // ---- load B fragments: weights (4n x 4kt) + x/bias (4n) ----
  half8 bw[4][4], bx[4];
  #pragma unroll
  for (int n=0;n<4;n++){
    #pragma unroll
    for (int t=0;t<4;t++){
      const int base = ((((lstm*8 + w)*4 + n)*4 + t)*64 + l)*8;
      bw[n][t] = *(const half8*)(Wfrag + base);
    }
    bx[n] = *(const half8*)(Bxfrag + (((lstm*8 + w)*4 + n)*64 + l)*8);
  }

  // ---- stage x A-frags (rows 0-7 real, 8-15 zero) + mask ----
  {
    const int t = tid >> 3, r = tid & 7;
    const int n = n0 + r, b = n >> 5, p = n & 31;
    float x0,x1,x2,x3;
    if (lstm == 0){
      x0 = rel[(t*B_+b)*64 + p]; x1 = rel[(t*B_+b)*64 + 32 + p];
      x2 = 0.f; x3 = 0.f;
    } else {
      const int i0 = t*N_ + n;
      x0 = pvx[i0]; x1 = pvy[i0]; x2 = pax[i0]; x3 = pay[i0];
    }
    half8 v;
    v[0]=(_Float16)x0; v[1]=(_Float16)x1; v[2]=(_Float16)x2; v[3]=(_Float16)x3;
    v[4]=(_Float16)1.f; v[5]=(_Float16)1.f; v[6]=(_Float16)0.f; v[7]=(_Float16)0.f;
    *(half8*)&axf[t][r][0] = v;
    half8 zz;
    #pragma unroll
    for (int q=0;q<8;q++) zz[q]=(_Float16)0.f;
    *(half8*)&axf[t][8+r][0] = zz;
    if (tid == 0) *(half8*)&zslot[0] = zz;
    if (tid < T_){
      unsigned int mw = 0;
      for (int rr=0; rr<8; rr++) mw |= (maskI[tid*N_ + n0 + rr] > 0) ? (1u<<rr) : 0u;
      ml[tid] = mw;
    }
  }
  // zero both h buffers (4096 f16 = 2048 u32)
  {
    unsigned int* hz = (unsigned int*)&hA[0][0][0][0];
    #pragma unroll
    for (int i=0;i<4;i++) hz[tid + i*512] = 0u;
  }

  // activation ownership: 2 real cells per lane
  const int halfw = l >> 5;
  const int rbase = ((l & 31) >> 4)*4 + 2*halfw;      // rows rbase, rbase+1 (0..7)
  const int lpp0  = rbase + 16*((u >> 3) & 3);
  const int hoff0 = kt_u*512 + lpp0*8 + (u & 7);      // halves
  const int hoff1 = hoff0 + 8;                         // row+1 -> lpp+1
  _Float16* hbase = &hA[0][0][0][0];
  const _Float16* axp_base = (l < 16) ? &axf[0][l][0] : &zslot[0];
  const int ax_stride = (l < 16) ? 128 : 0;            // halves per t

  float cc0 = 0.f, cc1 = 0.f;
  _Float16 rh0 = (_Float16)0.f, rh1 = (_Float16)0.f;
  __syncthreads();

  const f32x4 zc = {0.f, 0.f, 0.f, 0.f};
  #pragma unroll 2
  for (int t=0; t<T_; ++t){
    const int cur = t & 1, nxt = cur ^ 1;
    const unsigned int mw = ml[t];

    // chain A: x/bias init + kt 0,2 ; chain B: kt 1,3 from zero; merge with add
    const half8 ax = *(const half8*)(axp_base + t*ax_stride);
    f32x4 accA[4], accB[4];
    #pragma unroll
    for (int n=0;n<4;n++)
      accA[n] = __builtin_amdgcn_mfma_f32_16x16x32_f16(ax, bx[n], zc, 0, 0, 0);

    half8 ah[4];
    #pragma unroll
    for (int kt=0;kt<4;kt++) ah[kt] = *(const half8*)&hA[cur][kt][l][0];

    #pragma unroll
    for (int n=0;n<4;n++)
      accA[n] = __builtin_amdgcn_mfma_f32_16x16x32_f16(ah[0], bw[n][0], accA[n], 0, 0, 0);
    #pragma unroll
    for (int n=0;n<4;n++)
      accB[n] = __builtin_amdgcn_mfma_f32_16x16x32_f16(ah[1], bw[n][1], zc, 0, 0, 0);
    #pragma unroll
    for (int n=0;n<4;n++)
      accA[n] = __builtin_amdgcn_mfma_f32_16x16x32_f16(ah[2], bw[n][2], accA[n], 0, 0, 0);
    #pragma unroll
    for (int n=0;n<4;n++)
      accB[n] = __builtin_amdgcn_mfma_f32_16x16x32_f16(ah[3], bw[n][3], accB[n], 0, 0, 0);

    f32x4 acc[4];
    #pragma unroll
    for (int n=0;n<4;n++) acc[n] = accA[n] + accB[n];

    // redistribute: upper half-wave takes rows r0+2,r0+3 from lower half
    float g0[4], g1[4];
    #pragma unroll
    for (int n=0;n<4;n++){
      const float s2 = __shfl_xor(acc[n][2], 32, 64);
      const float s3 = __shfl_xor(acc[n][3], 32, 64);
      g0[n] = halfw ? s2 : acc[n][0];
      g1[n] = halfw ? s3 : acc[n][1];
    }

    // two real-cell activations (gate order: 0=i,1=f,2=g,3=o)
    {
      const float cn = sigm(g0[1])*cc0 + sigm(g0[0])*tanh_fast(g0[2]);
      const float hn = sigm(g0[3])*tanh_fast(cn);
      const int mb = (mw >> rbase) & 1;
      cc0 = mb ? cn : cc0;
      rh0 = mb ? (_Float16)hn : rh0;
      hbase[nxt*2048 + hoff0] = rh0;
    }
    {
      const float cn = sigm(g1[1])*cc1 + sigm(g1[0])*tanh_fast(g1[2]);
      const float hn = sigm(g1[3])*tanh_fast(cn);
      const int mb = (mw >> (rbase+1)) & 1;
      cc1 = mb ? cn : cc1;
      rh1 = mb ? (_Float16)hn : rh1;
      hbase[nxt*2048 + hoff1] = rh1;
    }
    __syncthreads();
  }

  // output this lane's two cells
  float* hout = lstm ? h_s_out : h_t_out;
  hout[(n0 + rbase    )*H_ + u] = (float)rh0;
  hout[(n0 + rbase + 1)*H_ + u] = (float)rh1;
}

// ---------------- Kernel 2: fused head — MLP + mean + attention + softmax + pool ----------------
// One block per batch b. 512 threads = 4 row-slots (rs) x 128 outputs (j).
// Reads F1/F2/A1 in natural row-major layout (thread j owns output j -> row j).
__global__ __launch_bounds__(512) void head_kernel(
    const float* __restrict__ h_t, const float* __restrict__ h_s,
    const int* __restrict__ maskI,
    const float* __restrict__ F1, const float* __restrict__ f1,
    const float* __restrict__ F2, const float* __restrict__ f2,
    const float* __restrict__ A1, const float* __restrict__ a1,
    const float* __restrict__ A2, const float* __restrict__ a2v,
    float* __restrict__ out)
{
  const int b = blockIdx.x, tid = threadIdx.x;
  const int rs = tid >> 7, j = tid & 127;
  __shared__ float comb[P_][2*H_];   // 32KB
  __shared__ float hid[P_][H_];      // 16KB
  __shared__ float fus[P_][H_];      // 16KB
  __shared__ float part[4][H_];      // 2KB
  __shared__ float okcnt[P_][16];    // 2KB
  __shared__ float okv[P_];
  __shared__ float sred[P_][2];
  __shared__ float wgt[P_];
  __shared__ float meansh[H_];
  __shared__ float nvsh;

  // load comb = [h_t | h_s] rows of this batch (float4, coalesced)
  #pragma unroll
  for (int i = 0; i < 4; ++i){
    const int f = tid + i*512;          // float4 index 0..2047
    const int r = f >> 6, c4 = f & 63;
    const float4 v = (c4 < 32)
      ? *(const float4*)(h_t + (size_t)(b*P_ + r)*H_ + c4*4)
      : *(const float4*)(h_s + (size_t)(b*P_ + r)*H_ + (c4-32)*4);
    *(float4*)&comb[r][c4*4] = v;
  }
  // ok per row: 512 threads, (p = tid>>4, tt = tid&15) sums 4 timesteps
  {
    const int p = tid >> 4, tt = tid & 15;
    int c = 0;
    #pragma unroll
    for (int q=0;q<4;q++) c += (maskI[(tt*4+q)*N_ + b*P_ + p] > 0);
    okcnt[p][tt] = (float)c;
  }
  __syncthreads();
  if (tid < P_){
    float c = 0.f;
    #pragma unroll
    for (int q=0;q<16;q++) c += okcnt[tid][q];
    okv[tid] = (c >= 2.f) ? 1.f : 0.f;
  }
  __syncthreads();
  if (tid == 0){
    float nv = 0.f;
    #pragma unroll
    for (int p=0;p<P_;p++) nv += okv[p];
    nvsh = fmaxf(nv, 1.f);
  }

  // F1: hid = relu(comb @ F1^T + f1)
  const float* F1r = F1 + (size_t)j*(2*H_);
  #pragma unroll 2
  for (int rg=0; rg<8; ++rg){
    const int r = rg*4 + rs;
    float acc = f1[j];
    #pragma unroll 8
    for (int k4=0;k4<64;k4++){
      const float4 cb = *(const float4*)&comb[r][k4*4];
      const float4 wv = *(const float4*)(F1r + k4*4);
      acc += cb.x*wv.x + cb.y*wv.y + cb.z*wv.z + cb.w*wv.w;
    }
    hid[r][j] = fmaxf(acc, 0.f);
  }
  __syncthreads();

  // F2: fus = relu(hid @ F2^T + f2) * ok
  const float* F2r = F2 + (size_t)j*H_;
  #pragma unroll 2
  for (int rg=0; rg<8; ++rg){
    const int r = rg*4 + rs;
    float acc = f2[j];
    #pragma unroll 8
    for (int k4=0;k4<32;k4++){
      const float4 cb = *(const float4*)&hid[r][k4*4];
      const float4 wv = *(const float4*)(F2r + k4*4);
      acc += cb.x*wv.x + cb.y*wv.y + cb.z*wv.z + cb.w*wv.w;
    }
    fus[r][j] = fmaxf(acc, 0.f) * okv[r];
  }
  __syncthreads();

  // mean over valid rows (invalid rows already zeroed)
  {
    float s = 0.f;
    #pragma unroll
    for (int r=rs*8; r<rs*8+8; ++r) s += fus[r][j];
    part[rs][j] = s;
  }
  __syncthreads();
  if (rs == 0) meansh[j] = (part[0][j]+part[1][j]+part[2][j]+part[3][j]) / nvsh;
  __syncthreads();

  // scores: per row r, score = relu(a2 + sum_j A2[j]*relu(a1[j] + att_in[r]·A1row_j))
  const float* A1r = A1 + (size_t)j*(2*H_);
  for (int rg=0; rg<8; ++rg){
    const int r = rg*4 + rs;
    float acc = a1[j];
    #pragma unroll 8
    for (int k4=0;k4<32;k4++){
      const float4 cb = *(const float4*)&fus[r][k4*4];
      const float4 wv = *(const float4*)(A1r + k4*4);
      acc += cb.x*wv.x + cb.y*wv.y + cb.z*wv.z + cb.w*wv.w;
    }
    #pragma unroll 8
    for (int k4=0;k4<32;k4++){
      const float4 cb = *(const float4*)&meansh[k4*4];
      const float4 wv = *(const float4*)(A1r + H_ + k4*4);
      acc += cb.x*wv.x + cb.y*wv.y + cb.z*wv.z + cb.w*wv.w;
    }
    float v = fmaxf(acc, 0.f) * A2[j];
    #pragma unroll
    for (int off=32; off>=1; off>>=1) v += __shfl_down(v, off, 64);
    if ((tid & 63) == 0) sred[r][j>>6] = v;
  }
  __syncthreads();

  // softmax over the 32 rows (lanes 0-31 of wave 0)
  if (tid < P_){
    float s = fmaxf(sred[tid][0] + sred[tid][1] + a2v[0], 0.f);
    s = (okv[tid] > 0.f) ? s : -1e9f;
    float mx = s;
    #pragma unroll
    for (int off=16; off>=1; off>>=1) mx = fmaxf(mx, __shfl_xor(mx, off, 32));
    const float e = (okv[tid] > 0.f) ? __expf(s - mx) : 0.f;
    float se = e;
    #pragma unroll
    for (int off=16; off>=1; off>>=1) se += __shfl_xor(se, off, 32);
    wgt[tid] = e / fmaxf(se, 1e-9f);
  }
  __syncthreads();

  // weighted pool
  {
    float s = 0.f;
    #pragma unroll
    for (int r=rs*8; r<rs*8+8; ++r) s += wgt[r]*fus[r][j];
    part[rs][j] = s;
  }
  __syncthreads();
  if (rs == 0) out[b*H_ + j] = part[0][j]+part[1][j]+part[2][j]+part[3][j];
}

extern "C" void kernel_launch(void* const* d_in, const int* in_sizes, int n_in,
                              void* d_out, int out_size, void* d_ws, size_t ws_size,
                              hipStream_t stream) {
  const float* rel   = (const float*)d_in[1];
  const float* pvx   = (const float*)d_in[2];
  const float* pvy   = (const float*)d_in[3];
  const float* pax   = (const float*)d_in[4];
  const float* pay   = (const float*)d_in[5];
  const int*   pmask = (const int*)  d_in[6];
  const float* W_sp  = (const float*)d_in[7];
  const float* b_sp  = (const float*)d_in[8];
  const float* W_st  = (const float*)d_in[9];
  const float* b_st  = (const float*)d_in[10];
  const float* Wih_t = (const float*)d_in[11];
  const float* Whh_t = (const float*)d_in[12];
  const float* bih_t = (const float*)d_in[13];
  const float* bhh_t = (const float*)d_in[14];
  const float* Wih_s = (const float*)d_in[15];
  const float* Whh_s = (const float*)d_in[16];
  const float* bih_s = (const float*)d_in[17];
  const float* bhh_s = (const float*)d_in[18];
  const float* A1    = (const float*)d_in[19];
  const float* a1    = (const float*)d_in[20];
  const float* A2    = (const float*)d_in[21];
  const float* a2v   = (const float*)d_in[22];
  const float* F1    = (const float*)d_in[23];
  const float* f1    = (const float*)d_in[24];
  const float* F2    = (const float*)d_in[25];
  const float* f2    = (const float*)d_in[26];

  float* ws = (float*)d_ws;
  size_t off = 0;
  _Float16* Wfrag  = (_Float16*)(ws + off); off += 65536;   // 131072 f16
  _Float16* Bxfrag = (_Float16*)(ws + off); off += 16384;   // 32768 f16
  float* h_t    = ws + off; off += (size_t)N_*H_;
  float* h_s    = ws + off; off += (size_t)N_*H_;

  hipLaunchKernelGGL(prep_kernel, dim3(9), dim3(256), 0, stream,
      W_sp, b_sp, W_st, b_st, Wih_t, Whh_t, bih_t, bhh_t,
      Wih_s, Whh_s, bih_s, bhh_s, Wfrag, Bxfrag);

  hipLaunchKernelGGL(lstm_kernel, dim3(N_/8, 2), dim3(512), 0, stream,
      rel, pvx, pvy, pax, pay, pmask,
      Wfrag, Bxfrag, h_t, h_s);

  hipLaunchKernelGGL(head_kernel, dim3(B_), dim3(512), 0, stream,
      h_t, h_s, pmask, F1, f1, F2, f2, A1, a1, A2, a2v, (float*)d_out);
}

// Round 9
// 122.792 us; speedup vs baseline: 2.9698x; 2.9698x over previous
//
#include <hip/hip_runtime.h>

#define T_ 64
#define B_ 32
#define P_ 32
#define N_ 1024
#define H_ 128
#define G_ 512   // 4*H

typedef __attribute__((ext_vector_type(8))) _Float16 half8;
typedef __attribute__((ext_vector_type(4))) float f32x4;

__device__ __forceinline__ float rcpf(float x){ return __builtin_amdgcn_rcpf(x); }
__device__ __forceinline__ float sigm(float x){ return rcpf(1.f+__expf(-x)); }
__device__ __forceinline__ float tanh_fast(float x){ return 1.f - 2.f*rcpf(__expf(2.f*x)+1.f); }

// ---------------- Kernel 0: prep (12 blocks) ----------------
// blk 0: Bx fragments (x-projection M + bias hi/lo folded as k-slots 0..5)
// blk 1-8: W fragments, f16, MFMA B-layout (as R7)
// blk 9: F1T, blk 10: F2T, blk 11: A1T (coalesced head layouts)
__global__ __launch_bounds__(256) void prep_kernel(
    const float* __restrict__ W_sp, const float* __restrict__ b_sp,
    const float* __restrict__ W_st, const float* __restrict__ b_st,
    const float* __restrict__ Wih_t, const float* __restrict__ Whh_t,
    const float* __restrict__ bih_t, const float* __restrict__ bhh_t,
    const float* __restrict__ Wih_s, const float* __restrict__ Whh_s,
    const float* __restrict__ bih_s, const float* __restrict__ bhh_s,
    const float* __restrict__ F1, const float* __restrict__ F2,
    const float* __restrict__ A1,
    _Float16* __restrict__ Wfrag, _Float16* __restrict__ Bxfrag,
    float* __restrict__ F1T, float* __restrict__ F2T, float* __restrict__ A1T)
{
  const int tid = threadIdx.x;
  const int blk = blockIdx.x;
  if (blk == 0) {
    unsigned int* bz = (unsigned int*)Bxfrag;
    for (int i = tid; i < 16384; i += 256) bz[i] = 0u;
    __syncthreads();
    for (int g = tid; g < G_; g += 256) {
      const int wv = (g & 127) >> 4, n = g >> 7, lane = g & 15;
      {
        float m0=0.f,m1=0.f,bt=0.f;
        for (int e=0;e<H_;e++){ float wgt=Wih_t[g*H_+e]; m0+=wgt*W_sp[e*2]; m1+=wgt*W_sp[e*2+1]; bt+=wgt*b_sp[e]; }
        const float bsum = bt + bih_t[g] + bhh_t[g];
        _Float16* dst = Bxfrag + (((0*8+wv)*4+n)*64 + lane)*8;
        dst[0]=(_Float16)m0; dst[1]=(_Float16)m1; dst[2]=(_Float16)0.f; dst[3]=(_Float16)0.f;
        const _Float16 bh = (_Float16)bsum;
        dst[4]=bh; dst[5]=(_Float16)(bsum-(float)bh);
      }
      {
        float s0=0.f,s1=0.f,s2=0.f,s3=0.f,bs=0.f;
        for (int e=0;e<H_;e++){ float wgt=Wih_s[g*H_+e]; s0+=wgt*W_st[e*4]; s1+=wgt*W_st[e*4+1]; s2+=wgt*W_st[e*4+2]; s3+=wgt*W_st[e*4+3]; bs+=wgt*b_st[e]; }
        const float bsum = bs + bih_s[g] + bhh_s[g];
        _Float16* dst = Bxfrag + (((1*8+wv)*4+n)*64 + lane)*8;
        dst[0]=(_Float16)s0; dst[1]=(_Float16)s1; dst[2]=(_Float16)s2; dst[3]=(_Float16)s3;
        const _Float16 bh = (_Float16)bsum;
        dst[4]=bh; dst[5]=(_Float16)(bsum-(float)bh);
      }
    }
  } else if (blk <= 8) {
    const int L = (blk-1) >> 2;           // lstm
    const int q = (blk-1) & 3;            // quarter
    const float* Whh = L ? Whh_s : Whh_t;
    for (int e = q*16384 + tid; e < (q+1)*16384; e += 256) {
      const int j  = e & 7;
      const int l  = (e >> 3) & 63;
      const int t  = (e >> 9) & 3;
      const int n  = (e >> 11) & 3;
      const int w  = (e >> 13) & 7;
      const int g  = n*128 + w*16 + (l & 15);
      const int k  = t*32 + 8*(l >> 4) + j;
      Wfrag[L*65536 + e] = (_Float16)Whh[g*H_ + k];
    }
  } else if (blk == 9) {
    for (int idx = tid; idx < H_*2*H_; idx += 256) { // F1 (128,256)
      int j = idx >> 8, k = idx & 255;
      F1T[k*H_+j] = F1[idx];
    }
  } else if (blk == 10) {
    for (int idx = tid; idx < H_*H_; idx += 256) {  // F2 (128,128)
      int j = idx >> 7, k = idx & 127;
      F2T[k*H_+j] = F2[idx];
    }
  } else {
    for (int idx = tid; idx < H_*2*H_; idx += 256) { // A1 (128,256)
      int j = idx >> 8, k = idx & 255;
      A1T[k*H_+j] = A1[idx];
    }
  }
}

// ---------------- Kernel 1: both masked LSTMs, MFMA (unchanged from R8) ----------------
__global__ __launch_bounds__(512) __attribute__((amdgpu_waves_per_eu(2,2)))
void lstm_kernel(
    const float* __restrict__ rel, const float* __restrict__ pvx,
    const float* __restrict__ pvy, const float* __restrict__ pax,
    const float* __restrict__ pay, const int* __restrict__ maskI,
    const _Float16* __restrict__ Wfrag, const _Float16* __restrict__ Bxfrag,
    float* __restrict__ h_t_out, float* __restrict__ h_s_out)
{
  __shared__ _Float16 hA[2][4][64][8] __align__(16);   // h f16, dbuf, 8KB
  __shared__ _Float16 axf[T_][16][8] __align__(16);    // x A-frags, 16KB
  __shared__ _Float16 zslot[8] __align__(16);
  __shared__ unsigned int ml[T_];

  const int lstm = blockIdx.y;
  const int tid  = threadIdx.x;
  const int w    = tid >> 6;
  const int l    = tid & 63;
  const int n0   = blockIdx.x * 8;
  const int u    = w*16 + (l & 15);
  const int kt_u = u >> 5;

  half8 bw[4][4], bx[4];
  #pragma unroll
  for (int n=0;n<4;n++){
    #pragma unroll
    for (int t=0;t<4;t++){
      const int base = ((((lstm*8 + w)*4 + n)*4 + t)*64 + l)*8;
      bw[n][t] = *(const half8*)(Wfrag + base);
    }
    bx[n] = *(const half8*)(Bxfrag + (((lstm*8 + w)*4 + n)*64 + l)*8);
  }

  {
    const int t = tid >> 3, r = tid & 7;
    const int n = n0 + r, b = n >> 5, p = n & 31;
    float x0,x1,x2,x3;
    if (lstm == 0){
      x0 = rel[(t*B_+b)*64 + p]; x1 = rel[(t*B_+b)*64 + 32 + p];
      x2 = 0.f; x3 = 0.f;
    } else {
      const int i0 = t*N_ + n;
      x0 = pvx[i0]; x1 = pvy[i0]; x2 = pax[i0]; x3 = pay[i0];
    }
    half8 v;
    v[0]=(_Float16)x0; v[1]=(_Float16)x1; v[2]=(_Float16)x2; v[3]=(_Float16)x3;
    v[4]=(_Float16)1.f; v[5]=(_Float16)1.f; v[6]=(_Float16)0.f; v[7]=(_Float16)0.f;
    *(half8*)&axf[t][r][0] = v;
    half8 zz;
    #pragma unroll
    for (int q=0;q<8;q++) zz[q]=(_Float16)0.f;
    *(half8*)&axf[t][8+r][0] = zz;
    if (tid == 0) *(half8*)&zslot[0] = zz;
    if (tid < T_){
      unsigned int mw = 0;
      for (int rr=0; rr<8; rr++) mw |= (maskI[tid*N_ + n0 + rr] > 0) ? (1u<<rr) : 0u;
      ml[tid] = mw;
    }
  }
  {
    unsigned int* hz = (unsigned int*)&hA[0][0][0][0];
    #pragma unroll
    for (int i=0;i<4;i++) hz[tid + i*512] = 0u;
  }

  const int halfw = l >> 5;
  const int rbase = ((l & 31) >> 4)*4 + 2*halfw;      // rows rbase, rbase+1 (0..7)
  const int lpp0  = rbase + 16*((u >> 3) & 3);
  const int hoff0 = kt_u*512 + lpp0*8 + (u & 7);      // halves
  const int hoff1 = hoff0 + 8;
  _Float16* hbase = &hA[0][0][0][0];
  const _Float16* axp_base = (l < 16) ? &axf[0][l][0] : &zslot[0];
  const int ax_stride = (l < 16) ? 128 : 0;

  float cc0 = 0.f, cc1 = 0.f;
  _Float16 rh0 = (_Float16)0.f, rh1 = (_Float16)0.f;
  __syncthreads();

  const f32x4 zc = {0.f, 0.f, 0.f, 0.f};
  #pragma unroll 2
  for (int t=0; t<T_; ++t){
    const int cur = t & 1, nxt = cur ^ 1;
    const unsigned int mw = ml[t];

    const half8 ax = *(const half8*)(axp_base + t*ax_stride);
    f32x4 accA[4], accB[4];
    #pragma unroll
    for (int n=0;n<4;n++)
      accA[n] = __builtin_amdgcn_mfma_f32_16x16x32_f16(ax, bx[n], zc, 0, 0, 0);

    half8 ah[4];
    #pragma unroll
    for (int kt=0;kt<4;kt++) ah[kt] = *(const half8*)&hA[cur][kt][l][0];

    #pragma unroll
    for (int n=0;n<4;n++)
      accA[n] = __builtin_amdgcn_mfma_f32_16x16x32_f16(ah[0], bw[n][0], accA[n], 0, 0, 0);
    #pragma unroll
    for (int n=0;n<4;n++)
      accB[n] = __builtin_amdgcn_mfma_f32_16x16x32_f16(ah[1], bw[n][1], zc, 0, 0, 0);
    #pragma unroll
    for (int n=0;n<4;n++)
      accA[n] = __builtin_amdgcn_mfma_f32_16x16x32_f16(ah[2], bw[n][2], accA[n], 0, 0, 0);
    #pragma unroll
    for (int n=0;n<4;n++)
      accB[n] = __builtin_amdgcn_mfma_f32_16x16x32_f16(ah[3], bw[n][3], accB[n], 0, 0, 0);

    f32x4 acc[4];
    #pragma unroll
    for (int n=0;n<4;n++) acc[n] = accA[n] + accB[n];

    float g0[4], g1[4];
    #pragma unroll
    for (int n=0;n<4;n++){
      const float s2 = __shfl_xor(acc[n][2], 32, 64);
      const float s3 = __shfl_xor(acc[n][3], 32, 64);
      g0[n] = halfw ? s2 : acc[n][0];
      g1[n] = halfw ? s3 : acc[n][1];
    }

    {
      const float cn = sigm(g0[1])*cc0 + sigm(g0[0])*tanh_fast(g0[2]);
      const float hn = sigm(g0[3])*tanh_fast(cn);
      const int mb = (mw >> rbase) & 1;
      cc0 = mb ? cn : cc0;
      rh0 = mb ? (_Float16)hn : rh0;
      hbase[nxt*2048 + hoff0] = rh0;
    }
    {
      const float cn = sigm(g1[1])*cc1 + sigm(g1[0])*tanh_fast(g1[2]);
      const float hn = sigm(g1[3])*tanh_fast(cn);
      const int mb = (mw >> (rbase+1)) & 1;
      cc1 = mb ? cn : cc1;
      rh1 = mb ? (_Float16)hn : rh1;
      hbase[nxt*2048 + hoff1] = rh1;
    }
    __syncthreads();
  }

  float* hout = lstm ? h_s_out : h_t_out;
  hout[(n0 + rbase    )*H_ + u] = (float)rh0;
  hout[(n0 + rbase + 1)*H_ + u] = (float)rh1;
}

// ---------------- Kernel 2: fused head, COALESCED weight reads ----------------
// One block per batch. 512 threads = 4 row-slots (rs) x 128 outputs (j).
// Weights via transposed layouts W[k*H+j]: lane j contiguous -> 256B/wave instr.
// comb/hid/fus read as wave-uniform LDS float2 broadcasts (conflict-free).
__global__ __launch_bounds__(512) void head_kernel(
    const float* __restrict__ h_t, const float* __restrict__ h_s,
    const int* __restrict__ maskI,
    const float* __restrict__ F1T, const float* __restrict__ f1,
    const float* __restrict__ F2T, const float* __restrict__ f2,
    const float* __restrict__ A1T, const float* __restrict__ a1,
    const float* __restrict__ A2, const float* __restrict__ a2v,
    float* __restrict__ out)
{
  const int b = blockIdx.x, tid = threadIdx.x;
  const int rs = tid >> 7, j = tid & 127;
  __shared__ float comb[P_][2*H_];   // 32KB
  __shared__ float hid[P_][H_];      // 16KB
  __shared__ float fus[P_][H_];      // 16KB
  __shared__ float part[4][H_];      // 2KB
  __shared__ float okcnt[P_][16];    // 2KB
  __shared__ float okv[P_];
  __shared__ float sred[P_][2];
  __shared__ float wgt[P_];
  __shared__ float meansh[H_];
  __shared__ float nvsh;

  // load comb = [h_t | h_s] rows of this batch (float4, coalesced)
  #pragma unroll
  for (int i = 0; i < 4; ++i){
    const int f = tid + i*512;          // float4 index 0..2047
    const int r = f >> 6, c4 = f & 63;
    const float4 v = (c4 < 32)
      ? *(const float4*)(h_t + (size_t)(b*P_ + r)*H_ + c4*4)
      : *(const float4*)(h_s + (size_t)(b*P_ + r)*H_ + (c4-32)*4);
    *(float4*)&comb[r][c4*4] = v;
  }
  // ok per row
  {
    const int p = tid >> 4, tt = tid & 15;
    int c = 0;
    #pragma unroll
    for (int q=0;q<4;q++) c += (maskI[(tt*4+q)*N_ + b*P_ + p] > 0);
    okcnt[p][tt] = (float)c;
  }
  __syncthreads();
  if (tid < P_){
    float c = 0.f;
    #pragma unroll
    for (int q=0;q<16;q++) c += okcnt[tid][q];
    okv[tid] = (c >= 2.f) ? 1.f : 0.f;
  }
  __syncthreads();
  if (tid == 0){
    float nv = 0.f;
    #pragma unroll
    for (int p=0;p<P_;p++) nv += okv[p];
    nvsh = fmaxf(nv, 1.f);
  }

  // F1: hid = relu(comb @ F1^T + f1); thread owns (rs, j), 8 rows each
  {
    float acc[8];
    #pragma unroll
    for (int rg=0;rg<8;rg++) acc[rg] = f1[j];
    for (int k2=0;k2<H_;k2++){
      const float w0 = F1T[(2*k2  )*H_ + j];
      const float w1 = F1T[(2*k2+1)*H_ + j];
      #pragma unroll
      for (int rg=0;rg<8;rg++){
        const float2 cb = *(const float2*)&comb[rg*4+rs][k2*2];
        acc[rg] += cb.x*w0 + cb.y*w1;
      }
    }
    #pragma unroll
    for (int rg=0;rg<8;rg++) hid[rg*4+rs][j] = fmaxf(acc[rg], 0.f);
  }
  __syncthreads();

  // F2: fus = relu(hid @ F2^T + f2) * ok
  {
    float acc[8];
    #pragma unroll
    for (int rg=0;rg<8;rg++) acc[rg] = f2[j];
    for (int k2=0;k2<64;k2++){
      const float w0 = F2T[(2*k2  )*H_ + j];
      const float w1 = F2T[(2*k2+1)*H_ + j];
      #pragma unroll
      for (int rg=0;rg<8;rg++){
        const float2 cb = *(const float2*)&hid[rg*4+rs][k2*2];
        acc[rg] += cb.x*w0 + cb.y*w1;
      }
    }
    #pragma unroll
    for (int rg=0;rg<8;rg++){
      const int r = rg*4+rs;
      fus[r][j] = fmaxf(acc[rg], 0.f) * okv[r];
    }
  }
  __syncthreads();

  // mean over valid rows (invalid rows already zeroed)
  {
    float s = 0.f;
    #pragma unroll
    for (int r=rs*8; r<rs*8+8; ++r) s += fus[r][j];
    part[rs][j] = s;
  }
  __syncthreads();
  if (rs == 0) meansh[j] = (part[0][j]+part[1][j]+part[2][j]+part[3][j]) / nvsh;
  __syncthreads();

  // scores: hidden unit j of attention MLP; mean term row-independent
  {
    float acc[8];
    #pragma unroll
    for (int rg=0;rg<8;rg++) acc[rg] = a1[j];
    for (int k2=0;k2<64;k2++){
      const float w0 = A1T[(2*k2  )*H_ + j];
      const float w1 = A1T[(2*k2+1)*H_ + j];
      #pragma unroll
      for (int rg=0;rg<8;rg++){
        const float2 cb = *(const float2*)&fus[rg*4+rs][k2*2];
        acc[rg] += cb.x*w0 + cb.y*w1;
      }
    }
    float mterm = 0.f;
    for (int k2=0;k2<64;k2++){
      const float w0 = A1T[(H_ + 2*k2  )*H_ + j];
      const float w1 = A1T[(H_ + 2*k2+1)*H_ + j];
      const float2 cb = *(const float2*)&meansh[k2*2];
      mterm += cb.x*w0 + cb.y*w1;
    }
    const float a2j = A2[j];
    #pragma unroll
    for (int rg=0;rg<8;rg++){
      float v = fmaxf(acc[rg] + mterm, 0.f) * a2j;
      #pragma unroll
      for (int off=32; off>=1; off>>=1) v += __shfl_down(v, off, 64);
      if ((tid & 63) == 0) sred[rg*4+rs][j>>6] = v;
    }
  }
  __syncthreads();

  // softmax over the 32 rows (lanes 0-31 of wave 0)
  if (tid < P_){
    float s = fmaxf(sred[tid][0] + sred[tid][1] + a2v[0], 0.f);
    s = (okv[tid] > 0.f) ? s : -1e9f;
    float mx = s;
    #pragma unroll
    for (int off=16; off>=1; off>>=1) mx = fmaxf(mx, __shfl_xor(mx, off, 32));
    const float e = (okv[tid] > 0.f) ? __expf(s - mx) : 0.f;
    float se = e;
    #pragma unroll
    for (int off=16; off>=1; off>>=1) se += __shfl_xor(se, off, 32);
    wgt[tid] = e / fmaxf(se, 1e-9f);
  }
  __syncthreads();

  // weighted pool
  {
    float s = 0.f;
    #pragma unroll
    for (int r=rs*8; r<rs*8+8; ++r) s += wgt[r]*fus[r][j];
    part[rs][j] = s;
  }
  __syncthreads();
  if (rs == 0) out[b*H_ + j] = part[0][j]+part[1][j]+part[2][j]+part[3][j];
}

extern "C" void kernel_launch(void* const* d_in, const int* in_sizes, int n_in,
                              void* d_out, int out_size, void* d_ws, size_t ws_size,
                              hipStream_t stream) {
  const float* rel   = (const float*)d_in[1];
  const float* pvx   = (const float*)d_in[2];
  const float* pvy   = (const float*)d_in[3];
  const float* pax   = (const float*)d_in[4];
  const float* pay   = (const float*)d_in[5];
  const int*   pmask = (const int*)  d_in[6];
  const float* W_sp  = (const float*)d_in[7];
  const float* b_sp  = (const float*)d_in[8];
  const float* W_st  = (const float*)d_in[9];
  const float* b_st  = (const float*)d_in[10];
  const float* Wih_t = (const float*)d_in[11];
  const float* Whh_t = (const float*)d_in[12];
  const float* bih_t = (const float*)d_in[13];
  const float* bhh_t = (const float*)d_in[14];
  const float* Wih_s = (const float*)d_in[15];
  const float* Whh_s = (const float*)d_in[16];
  const float* bih_s = (const float*)d_in[17];
  const float* bhh_s = (const float*)d_in[18];
  const float* A1    = (const float*)d_in[19];
  const float* a1    = (const float*)d_in[20];
  const float* A2    = (const float*)d_in[21];
  const float* a2v   = (const float*)d_in[22];
  const float* F1    = (const float*)d_in[23];
  const float* f1    = (const float*)d_in[24];
  const float* F2    = (const float*)d_in[25];
  const float* f2    = (const float*)d_in[26];

  float* ws = (float*)d_ws;
  size_t off = 0;
  _Float16* Wfrag  = (_Float16*)(ws + off); off += 65536;   // 131072 f16
  _Float16* Bxfrag = (_Float16*)(ws + off); off += 16384;   // 32768 f16
  float* F1T    = ws + off; off += (size_t)2*H_*H_;
  float* F2T    = ws + off; off += (size_t)H_*H_;
  float* A1T    = ws + off; off += (size_t)2*H_*H_;
  float* h_t    = ws + off; off += (size_t)N_*H_;
  float* h_s    = ws + off; off += (size_t)N_*H_;

  hipLaunchKernelGGL(prep_kernel, dim3(12), dim3(256), 0, stream,
      W_sp, b_sp, W_st, b_st, Wih_t, Whh_t, bih_t, bhh_t,
      Wih_s, Whh_s, bih_s, bhh_s, F1, F2, A1,
      Wfrag, Bxfrag, F1T, F2T, A1T);

  hipLaunchKernelGGL(lstm_kernel, dim3(N_/8, 2), dim3(512), 0, stream,
      rel, pvx, pvy, pax, pay, pmask,
      Wfrag, Bxfrag, h_t, h_s);

  hipLaunchKernelGGL(head_kernel, dim3(B_), dim3(512), 0, stream,
      h_t, h_s, pmask, F1T, f1, F2T, f2, A1T, a1, A2, a2v, (float*)d_out);
}

// Round 10
// 99.108 us; speedup vs baseline: 3.6795x; 1.2390x over previous
//
#include <hip/hip_runtime.h>

#define T_ 64
#define B_ 32
#define P_ 32
#define N_ 1024
#define H_ 128
#define G_ 512   // 4*H

typedef __attribute__((ext_vector_type(8))) _Float16 half8;
typedef __attribute__((ext_vector_type(4))) float f32x4;

__device__ __forceinline__ float rcpf(float x){ return __builtin_amdgcn_rcpf(x); }
__device__ __forceinline__ float sigm(float x){ return rcpf(1.f+__expf(-x)); }
__device__ __forceinline__ float tanh_fast(float x){ return 1.f - 2.f*rcpf(__expf(2.f*x)+1.f); }

// ---------------- Kernel 0: prep (36 parallel blocks) ----------------
// blk 0-7 : Bx fragments; L = blk>>2, gate-type q = blk&3 (g in [q*128,q*128+128))
//           Wih rows LDS-staged (coalesced), pad-129 rows -> conflict-free dot
// blk 8-15: W fragments, f16, MFMA B-layout (unchanged)
// blk 16-23: F1T 64x64 LDS-tiled transpose; 24-27: F2T; 28-35: A1T
__global__ __launch_bounds__(256) void prep_kernel(
    const float* __restrict__ W_sp, const float* __restrict__ b_sp,
    const float* __restrict__ W_st, const float* __restrict__ b_st,
    const float* __restrict__ Wih_t, const float* __restrict__ Whh_t,
    const float* __restrict__ bih_t, const float* __restrict__ bhh_t,
    const float* __restrict__ Wih_s, const float* __restrict__ Whh_s,
    const float* __restrict__ bih_s, const float* __restrict__ bhh_s,
    const float* __restrict__ F1, const float* __restrict__ F2,
    const float* __restrict__ A1,
    _Float16* __restrict__ Wfrag, _Float16* __restrict__ Bxfrag,
    float* __restrict__ F1T, float* __restrict__ F2T, float* __restrict__ A1T)
{
  __shared__ float Wl[128][129];       // 66KB (aliased as transpose tile)
  __shared__ float spw[512];
  __shared__ float bsm[128];
  __shared__ float prt[128][8];
  float (*tile)[65] = (float(*)[65])&Wl[0][0];

  const int tid = threadIdx.x;
  const int blk = blockIdx.x;

  if (blk < 8) {
    const int L = blk >> 2, q = blk & 3;
    const int g0 = q*128;
    const float* Wih = L ? Wih_s : Wih_t;
    // zero this block's Bx slice (wv 0..7, n=q): 2048 u32
    {
      unsigned int* Bz = (unsigned int*)Bxfrag;
      for (int i = tid; i < 2048; i += 256){
        const int wv = i >> 8, word = i & 255;
        Bz[((L*8+wv)*4+q)*256 + word] = 0u;
      }
    }
    // stage small weights
    if (L == 0){
      if (tid < 256) spw[tid] = W_sp[tid];
      if (tid < 128) bsm[tid] = b_sp[tid];
    } else {
      spw[tid] = W_st[tid]; spw[256+tid] = W_st[256+tid];
      if (tid < 128) bsm[tid] = b_st[tid];
    }
    // stage Wih rows g0..g0+127 (coalesced float4 loads, scalar LDS stores)
    for (int idx = tid; idx < 4096; idx += 256){
      const int r = idx >> 5, c4 = idx & 31;
      const float4 v = *(const float4*)(Wih + (size_t)(g0+r)*H_ + c4*4);
      Wl[r][c4*4+0]=v.x; Wl[r][c4*4+1]=v.y; Wl[r][c4*4+2]=v.z; Wl[r][c4*4+3]=v.w;
    }
    __syncthreads();
    // dot: thread (g_l = tid&127, half = tid>>7) covers e in [half*64, half*64+64)
    const int g_l = tid & 127, half = tid >> 7, e0 = half*64;
    float a0=0.f,a1v=0.f,a2=0.f,a3=0.f,ab=0.f;
    if (L == 0){
      for (int e=e0; e<e0+64; ++e){
        const float wv = Wl[g_l][e];
        a0 += wv*spw[e*2]; a1v += wv*spw[e*2+1]; ab += wv*bsm[e];
      }
    } else {
      for (int e=e0; e<e0+64; ++e){
        const float wv = Wl[g_l][e];
        a0 += wv*spw[e*4]; a1v += wv*spw[e*4+1]; a2 += wv*spw[e*4+2]; a3 += wv*spw[e*4+3];
        ab += wv*bsm[e];
      }
    }
    if (half == 1){ prt[g_l][0]=a0; prt[g_l][1]=a1v; prt[g_l][2]=a2; prt[g_l][3]=a3; prt[g_l][4]=ab; }
    __syncthreads();
    if (half == 0){
      a0 += prt[g_l][0]; a1v += prt[g_l][1]; a2 += prt[g_l][2]; a3 += prt[g_l][3]; ab += prt[g_l][4];
      const int g = g0 + g_l;
      const float bsum = ab + (L ? bih_s[g] : bih_t[g]) + (L ? bhh_s[g] : bhh_t[g]);
      const int wv = g_l >> 4, lane = g_l & 15;
      _Float16* dst = Bxfrag + (size_t)(((L*8+wv)*4+q)*64 + lane)*8;
      if (L == 0){
        dst[0]=(_Float16)a0; dst[1]=(_Float16)a1v; dst[2]=(_Float16)0.f; dst[3]=(_Float16)0.f;
      } else {
        dst[0]=(_Float16)a0; dst[1]=(_Float16)a1v; dst[2]=(_Float16)a2; dst[3]=(_Float16)a3;
      }
      const _Float16 bh = (_Float16)bsum;
      dst[4]=bh; dst[5]=(_Float16)(bsum-(float)bh);
    }
  } else if (blk < 16) {
    const int ib = blk - 8;
    const int L = ib >> 2;            // lstm
    const int q = ib & 3;             // quarter
    const float* Whh = L ? Whh_s : Whh_t;
    for (int e = q*16384 + tid; e < (q+1)*16384; e += 256) {
      const int j  = e & 7;
      const int l  = (e >> 3) & 63;
      const int t  = (e >> 9) & 3;
      const int n  = (e >> 11) & 3;
      const int w  = (e >> 13) & 7;
      const int g  = n*128 + w*16 + (l & 15);
      const int k  = t*32 + 8*(l >> 4) + j;
      Wfrag[L*65536 + e] = (_Float16)Whh[g*H_ + k];
    }
  } else {
    // LDS-tiled 64x64 transpose: dst[k*S + j] = src[j*C + k]
    const float* src; float* dst; int C, S, local;
    if (blk < 24){ src = F1; dst = F1T; C = 2*H_; S = H_; local = blk-16; }
    else if (blk < 28){ src = F2; dst = F2T; C = H_; S = H_; local = blk-24; }
    else { src = A1; dst = A1T; C = 2*H_; S = H_; local = blk-28; }
    const int r0 = (C == 2*H_) ? (local>>2)*64 : (local>>1)*64;
    const int c0 = (C == 2*H_) ? (local&3)*64  : (local&1)*64;
    for (int i=0;i<4;i++){
      const int idx = tid + i*256;
      const int r = idx >> 4, c4 = idx & 15;
      const float4 v = *(const float4*)(src + (size_t)(r0+r)*C + c0 + c4*4);
      tile[r][c4*4+0]=v.x; tile[r][c4*4+1]=v.y; tile[r][c4*4+2]=v.z; tile[r][c4*4+3]=v.w;
    }
    __syncthreads();
    for (int i=0;i<4;i++){
      const int idx = tid + i*256;
      const int c = idx >> 4, r4 = idx & 15;
      float4 o;
      o.x = tile[r4*4+0][c]; o.y = tile[r4*4+1][c];
      o.z = tile[r4*4+2][c]; o.w = tile[r4*4+3][c];
      *(float4*)(dst + (size_t)(c0+c)*S + r0 + r4*4) = o;
    }
  }
}

// ---------------- Kernel 1: both masked LSTMs, MFMA (R7 sequential chain) ----------------
__global__ __launch_bounds__(512) __attribute__((amdgpu_waves_per_eu(2,2)))
void lstm_kernel(
    const float* __restrict__ rel, const float* __restrict__ pvx,
    const float* __restrict__ pvy, const float* __restrict__ pax,
    const float* __restrict__ pay, const int* __restrict__ maskI,
    const _Float16* __restrict__ Wfrag, const _Float16* __restrict__ Bxfrag,
    float* __restrict__ h_t_out, float* __restrict__ h_s_out)
{
  __shared__ _Float16 hA[2][4][64][8] __align__(16);   // h f16, dbuf, 8KB
  __shared__ _Float16 axf[T_][16][8] __align__(16);    // x A-frags, 16KB
  __shared__ _Float16 zslot[8] __align__(16);
  __shared__ unsigned int ml[T_];

  const int lstm = blockIdx.y;
  const int tid  = threadIdx.x;
  const int w    = tid >> 6;
  const int l    = tid & 63;
  const int n0   = blockIdx.x * 8;
  const int u    = w*16 + (l & 15);
  const int kt_u = u >> 5;

  half8 bw[4][4], bx[4];
  #pragma unroll
  for (int n=0;n<4;n++){
    #pragma unroll
    for (int t=0;t<4;t++){
      const int base = ((((lstm*8 + w)*4 + n)*4 + t)*64 + l)*8;
      bw[n][t] = *(const half8*)(Wfrag + base);
    }
    bx[n] = *(const half8*)(Bxfrag + (((lstm*8 + w)*4 + n)*64 + l)*8);
  }

  {
    const int t = tid >> 3, r = tid & 7;
    const int n = n0 + r, b = n >> 5, p = n & 31;
    float x0,x1,x2,x3;
    if (lstm == 0){
      x0 = rel[(t*B_+b)*64 + p]; x1 = rel[(t*B_+b)*64 + 32 + p];
      x2 = 0.f; x3 = 0.f;
    } else {
      const int i0 = t*N_ + n;
      x0 = pvx[i0]; x1 = pvy[i0]; x2 = pax[i0]; x3 = pay[i0];
    }
    half8 v;
    v[0]=(_Float16)x0; v[1]=(_Float16)x1; v[2]=(_Float16)x2; v[3]=(_Float16)x3;
    v[4]=(_Float16)1.f; v[5]=(_Float16)1.f; v[6]=(_Float16)0.f; v[7]=(_Float16)0.f;
    *(half8*)&axf[t][r][0] = v;
    half8 zz;
    #pragma unroll
    for (int q=0;q<8;q++) zz[q]=(_Float16)0.f;
    *(half8*)&axf[t][8+r][0] = zz;
    if (tid == 0) *(half8*)&zslot[0] = zz;
    if (tid < T_){
      unsigned int mw = 0;
      for (int rr=0; rr<8; rr++) mw |= (maskI[tid*N_ + n0 + rr] > 0) ? (1u<<rr) : 0u;
      ml[tid] = mw;
    }
  }
  {
    unsigned int* hz = (unsigned int*)&hA[0][0][0][0];
    #pragma unroll
    for (int i=0;i<4;i++) hz[tid + i*512] = 0u;
  }

  const int halfw = l >> 5;
  const int rbase = ((l & 31) >> 4)*4 + 2*halfw;      // rows rbase, rbase+1 (0..7)
  const int lpp0  = rbase + 16*((u >> 3) & 3);
  const int hoff0 = kt_u*512 + lpp0*8 + (u & 7);      // halves
  const int hoff1 = hoff0 + 8;
  _Float16* hbase = &hA[0][0][0][0];
  const _Float16* axp_base = (l < 16) ? &axf[0][l][0] : &zslot[0];
  const int ax_stride = (l < 16) ? 128 : 0;

  float cc0 = 0.f, cc1 = 0.f;
  _Float16 rh0 = (_Float16)0.f, rh1 = (_Float16)0.f;
  __syncthreads();

  const f32x4 zc = {0.f, 0.f, 0.f, 0.f};
  #pragma unroll 2
  for (int t=0; t<T_; ++t){
    const int cur = t & 1, nxt = cur ^ 1;
    const unsigned int mw = ml[t];

    const half8 ax = *(const half8*)(axp_base + t*ax_stride);
    f32x4 acc[4];
    #pragma unroll
    for (int n=0;n<4;n++)
      acc[n] = __builtin_amdgcn_mfma_f32_16x16x32_f16(ax, bx[n], zc, 0, 0, 0);

    half8 ah[4];
    #pragma unroll
    for (int kt=0;kt<4;kt++) ah[kt] = *(const half8*)&hA[cur][kt][l][0];

    #pragma unroll
    for (int kt=0;kt<4;kt++)
      #pragma unroll
      for (int n=0;n<4;n++)
        acc[n] = __builtin_amdgcn_mfma_f32_16x16x32_f16(ah[kt], bw[n][kt], acc[n], 0, 0, 0);

    float g0[4], g1[4];
    #pragma unroll
    for (int n=0;n<4;n++){
      const float s2 = __shfl_xor(acc[n][2], 32, 64);
      const float s3 = __shfl_xor(acc[n][3], 32, 64);
      g0[n] = halfw ? s2 : acc[n][0];
      g1[n] = halfw ? s3 : acc[n][1];
    }

    {
      const float cn = sigm(g0[1])*cc0 + sigm(g0[0])*tanh_fast(g0[2]);
      const float hn = sigm(g0[3])*tanh_fast(cn);
      const int mb = (mw >> rbase) & 1;
      cc0 = mb ? cn : cc0;
      rh0 = mb ? (_Float16)hn : rh0;
      hbase[nxt*2048 + hoff0] = rh0;
    }
    {
      const float cn = sigm(g1[1])*cc1 + sigm(g1[0])*tanh_fast(g1[2]);
      const float hn = sigm(g1[3])*tanh_fast(cn);
      const int mb = (mw >> (rbase+1)) & 1;
      cc1 = mb ? cn : cc1;
      rh1 = mb ? (_Float16)hn : rh1;
      hbase[nxt*2048 + hoff1] = rh1;
    }
    __syncthreads();
  }

  float* hout = lstm ? h_s_out : h_t_out;
  hout[(n0 + rbase    )*H_ + u] = (float)rh0;
  hout[(n0 + rbase + 1)*H_ + u] = (float)rh1;
}

// ---------------- Kernel 2: fused head, coalesced weights (unchanged from R9) ----------------
__global__ __launch_bounds__(512) void head_kernel(
    const float* __restrict__ h_t, const float* __restrict__ h_s,
    const int* __restrict__ maskI,
    const float* __restrict__ F1T, const float* __restrict__ f1,
    const float* __restrict__ F2T, const float* __restrict__ f2,
    const float* __restrict__ A1T, const float* __restrict__ a1,
    const float* __restrict__ A2, const float* __restrict__ a2v,
    float* __restrict__ out)
{
  const int b = blockIdx.x, tid = threadIdx.x;
  const int rs = tid >> 7, j = tid & 127;
  __shared__ float comb[P_][2*H_];   // 32KB
  __shared__ float hid[P_][H_];      // 16KB
  __shared__ float fus[P_][H_];      // 16KB
  __shared__ float part[4][H_];      // 2KB
  __shared__ float okcnt[P_][16];    // 2KB
  __shared__ float okv[P_];
  __shared__ float sred[P_][2];
  __shared__ float wgt[P_];
  __shared__ float meansh[H_];
  __shared__ float nvsh;

  #pragma unroll
  for (int i = 0; i < 4; ++i){
    const int f = tid + i*512;
    const int r = f >> 6, c4 = f & 63;
    const float4 v = (c4 < 32)
      ? *(const float4*)(h_t + (size_t)(b*P_ + r)*H_ + c4*4)
      : *(const float4*)(h_s + (size_t)(b*P_ + r)*H_ + (c4-32)*4);
    *(float4*)&comb[r][c4*4] = v;
  }
  {
    const int p = tid >> 4, tt = tid & 15;
    int c = 0;
    #pragma unroll
    for (int q=0;q<4;q++) c += (maskI[(tt*4+q)*N_ + b*P_ + p] > 0);
    okcnt[p][tt] = (float)c;
  }
  __syncthreads();
  if (tid < P_){
    float c = 0.f;
    #pragma unroll
    for (int q=0;q<16;q++) c += okcnt[tid][q];
    okv[tid] = (c >= 2.f) ? 1.f : 0.f;
  }
  __syncthreads();
  if (tid == 0){
    float nv = 0.f;
    #pragma unroll
    for (int p=0;p<P_;p++) nv += okv[p];
    nvsh = fmaxf(nv, 1.f);
  }

  {
    float acc[8];
    #pragma unroll
    for (int rg=0;rg<8;rg++) acc[rg] = f1[j];
    for (int k2=0;k2<H_;k2++){
      const float w0 = F1T[(2*k2  )*H_ + j];
      const float w1 = F1T[(2*k2+1)*H_ + j];
      #pragma unroll
      for (int rg=0;rg<8;rg++){
        const float2 cb = *(const float2*)&comb[rg*4+rs][k2*2];
        acc[rg] += cb.x*w0 + cb.y*w1;
      }
    }
    #pragma unroll
    for (int rg=0;rg<8;rg++) hid[rg*4+rs][j] = fmaxf(acc[rg], 0.f);
  }
  __syncthreads();

  {
    float acc[8];
    #pragma unroll
    for (int rg=0;rg<8;rg++) acc[rg] = f2[j];
    for (int k2=0;k2<64;k2++){
      const float w0 = F2T[(2*k2  )*H_ + j];
      const float w1 = F2T[(2*k2+1)*H_ + j];
      #pragma unroll
      for (int rg=0;rg<8;rg++){
        const float2 cb = *(const float2*)&hid[rg*4+rs][k2*2];
        acc[rg] += cb.x*w0 + cb.y*w1;
      }
    }
    #pragma unroll
    for (int rg=0;rg<8;rg++){
      const int r = rg*4+rs;
      fus[r][j] = fmaxf(acc[rg], 0.f) * okv[r];
    }
  }
  __syncthreads();

  {
    float s = 0.f;
    #pragma unroll
    for (int r=rs*8; r<rs*8+8; ++r) s += fus[r][j];
    part[rs][j] = s;
  }
  __syncthreads();
  if (rs == 0) meansh[j] = (part[0][j]+part[1][j]+part[2][j]+part[3][j]) / nvsh;
  __syncthreads();

  {
    float acc[8];
    #pragma unroll
    for (int rg=0;rg<8;rg++) acc[rg] = a1[j];
    for (int k2=0;k2<64;k2++){
      const float w0 = A1T[(2*k2  )*H_ + j];
      const float w1 = A1T[(2*k2+1)*H_ + j];
      #pragma unroll
      for (int rg=0;rg<8;rg++){
        const float2 cb = *(const float2*)&fus[rg*4+rs][k2*2];
        acc[rg] += cb.x*w0 + cb.y*w1;
      }
    }
    float mterm = 0.f;
    for (int k2=0;k2<64;k2++){
      const float w0 = A1T[(H_ + 2*k2  )*H_ + j];
      const float w1 = A1T[(H_ + 2*k2+1)*H_ + j];
      const float2 cb = *(const float2*)&meansh[k2*2];
      mterm += cb.x*w0 + cb.y*w1;
    }
    const float a2j = A2[j];
    #pragma unroll
    for (int rg=0;rg<8;rg++){
      float v = fmaxf(acc[rg] + mterm, 0.f) * a2j;
      #pragma unroll
      for (int off=32; off>=1; off>>=1) v += __shfl_down(v, off, 64);
      if ((tid & 63) == 0) sred[rg*4+rs][j>>6] = v;
    }
  }
  __syncthreads();

  if (tid < P_){
    float s = fmaxf(sred[tid][0] + sred[tid][1] + a2v[0], 0.f);
    s = (okv[tid] > 0.f) ? s : -1e9f;
    float mx = s;
    #pragma unroll
    for (int off=16; off>=1; off>>=1) mx = fmaxf(mx, __shfl_xor(mx, off, 32));
    const float e = (okv[tid] > 0.f) ? __expf(s - mx) : 0.f;
    float se = e;
    #pragma unroll
    for (int off=16; off>=1; off>>=1) se += __shfl_xor(se, off, 32);
    wgt[tid] = e / fmaxf(se, 1e-9f);
  }
  __syncthreads();

  {
    float s = 0.f;
    #pragma unroll
    for (int r=rs*8; r<rs*8+8; ++r) s += wgt[r]*fus[r][j];
    part[rs][j] = s;
  }
  __syncthreads();
  if (rs == 0) out[b*H_ + j] = part[0][j]+part[1][j]+part[2][j]+part[3][j];
}

extern "C" void kernel_launch(void* const* d_in, const int* in_sizes, int n_in,
                              void* d_out, int out_size, void* d_ws, size_t ws_size,
                              hipStream_t stream) {
  const float* rel   = (const float*)d_in[1];
  const float* pvx   = (const float*)d_in[2];
  const float* pvy   = (const float*)d_in[3];
  const float* pax   = (const float*)d_in[4];
  const float* pay   = (const float*)d_in[5];
  const int*   pmask = (const int*)  d_in[6];
  const float* W_sp  = (const float*)d_in[7];
  const float* b_sp  = (const float*)d_in[8];
  const float* W_st  = (const float*)d_in[9];
  const float* b_st  = (const float*)d_in[10];
  const float* Wih_t = (const float*)d_in[11];
  const float* Whh_t = (const float*)d_in[12];
  const float* bih_t = (const float*)d_in[13];
  const float* bhh_t = (const float*)d_in[14];
  const float* Wih_s = (const float*)d_in[15];
  const float* Whh_s = (const float*)d_in[16];
  const float* bih_s = (const float*)d_in[17];
  const float* bhh_s = (const float*)d_in[18];
  const float* A1    = (const float*)d_in[19];
  const float* a1    = (const float*)d_in[20];
  const float* A2    = (const float*)d_in[21];
  const float* a2v   = (const float*)d_in[22];
  const float* F1    = (const float*)d_in[23];
  const float* f1    = (const float*)d_in[24];
  const float* F2    = (const float*)d_in[25];
  const float* f2    = (const float*)d_in[26];

  float* ws = (float*)d_ws;
  size_t off = 0;
  _Float16* Wfrag  = (_Float16*)(ws + off); off += 65536;   // 131072 f16
  _Float16* Bxfrag = (_Float16*)(ws + off); off += 16384;   // 32768 f16
  float* F1T    = ws + off; off += (size_t)2*H_*H_;
  float* F2T    = ws + off; off += (size_t)H_*H_;
  float* A1T    = ws + off; off += (size_t)2*H_*H_;
  float* h_t    = ws + off; off += (size_t)N_*H_;
  float* h_s    = ws + off; off += (size_t)N_*H_;

  hipLaunchKernelGGL(prep_kernel, dim3(36), dim3(256), 0, stream,
      W_sp, b_sp, W_st, b_st, Wih_t, Whh_t, bih_t, bhh_t,
      Wih_s, Whh_s, bih_s, bhh_s, F1, F2, A1,
      Wfrag, Bxfrag, F1T, F2T, A1T);

  hipLaunchKernelGGL(lstm_kernel, dim3(N_/8, 2), dim3(512), 0, stream,
      rel, pvx, pvy, pax, pay, pmask,
      Wfrag, Bxfrag, h_t, h_s);

  hipLaunchKernelGGL(head_kernel, dim3(B_), dim3(512), 0, stream,
      h_t, h_s, pmask, F1T, f1, F2T, f2, A1T, a1, A2, a2v, (float*)d_out);
}